// Round 11
// baseline (101.422 us; speedup 1.0000x reference)
//
#include <hip/hip_runtime.h>
#include <hip/hip_bf16.h>
#include <math.h>

// Shapes
#define QL 32768
#define DD 1024
#define NTOK 64

using short8   = __attribute__((ext_vector_type(8))) short;
using f32x4    = __attribute__((ext_vector_type(4))) float;
using float4v  = __attribute__((ext_vector_type(4))) float;
using ushort4v = __attribute__((ext_vector_type(4))) unsigned short;

// RNE f32->bf16 via bit trick (exact RNE)
__device__ __forceinline__ unsigned short f2bf(float f) {
    unsigned int u = __float_as_uint(f);
    unsigned int r = (u + 0x7FFFu + ((u >> 16) & 1u)) >> 16;
    return (unsigned short)r;
}

// async global->LDS, 16B per lane; dest = wave-uniform base + lane*16
__device__ __forceinline__ void gload_lds16(const void* g, void* l) {
    __builtin_amdgcn_global_load_lds(
        (const __attribute__((address_space(1))) void*)g,
        (__attribute__((address_space(3))) void*)l,
        16, 0, 0);
}

// ---------------------------------------------------------------------------
// Prologue 1: transpose-convert Wq -> WqT bf16, Pv -> PvT bf16.
// ---------------------------------------------------------------------------
__global__ __launch_bounds__(256) void prep_transpose_kernel(
        const float* __restrict__ Wq, const float* __restrict__ Pv,
        unsigned short* __restrict__ WqT, unsigned short* __restrict__ PvT) {
    __shared__ float tile[64][65];
    int b = blockIdx.x;
    const float* src; unsigned short* dst; int R, C, r0, c0;
    if (b < 256) { src = Wq; dst = WqT; R = 1024; C = 1024;
                   r0 = (b >> 4) << 6; c0 = (b & 15) << 6; }
    else         { b -= 256; src = Pv; dst = PvT; R = 64; C = 1024;
                   r0 = 0; c0 = b << 6; }
    const int tid = threadIdx.x;
#pragma unroll
    for (int i = 0; i < 16; ++i) {
        const int lin = tid + 256 * i;
        const int row = lin >> 6, col = lin & 63;
        if (r0 + row < R)
            tile[row][col] = src[(size_t)(r0 + row) * C + c0 + col];
    }
    __syncthreads();
#pragma unroll
    for (int i = 0; i < 16; ++i) {
        const int lin = tid + 256 * i;
        const int row = lin >> 6, col = lin & 63;
        if (r0 + col < R)
            dst[(size_t)(c0 + row) * R + r0 + col] = f2bf(tile[col][row]);
    }
}

// ---------------------------------------------------------------------------
// Prologue 2: Kp = Pk @ Wq via bf16 MFMA (B from WqT). grid 16 x 256.
// ---------------------------------------------------------------------------
__global__ __launch_bounds__(256) void kp_mfma_kernel(
        const float* __restrict__ Pk, const unsigned short* __restrict__ WqT,
        unsigned short* __restrict__ Kp) {
    const int tid = threadIdx.x;
    const int w   = tid >> 6;
    const int l   = tid & 63;
    const int lhi = l >> 4;
    const int llo = l & 15;
    const int N0  = blockIdx.x * 64;

    f32x4 acc[4];
#pragma unroll
    for (int ct = 0; ct < 4; ++ct) acc[ct] = (f32x4){0.f, 0.f, 0.f, 0.f};

    for (int kb = 0; kb < 32; ++kb) {
        const int k0 = kb * 32 + lhi * 8;
        float4v p0 = *(const float4v*)(Pk + (size_t)(w * 16 + llo) * DD + k0);
        float4v p1 = *(const float4v*)(Pk + (size_t)(w * 16 + llo) * DD + k0 + 4);
        short8 a;
        a[0] = (short)f2bf(p0.x); a[1] = (short)f2bf(p0.y);
        a[2] = (short)f2bf(p0.z); a[3] = (short)f2bf(p0.w);
        a[4] = (short)f2bf(p1.x); a[5] = (short)f2bf(p1.y);
        a[6] = (short)f2bf(p1.z); a[7] = (short)f2bf(p1.w);
#pragma unroll
        for (int ct = 0; ct < 4; ++ct) {
            short8 b = *(const short8*)(WqT + (size_t)(N0 + ct * 16 + llo) * DD + k0);
            acc[ct] = __builtin_amdgcn_mfma_f32_16x16x32_bf16(a, b, acc[ct], 0, 0, 0);
        }
    }
#pragma unroll
    for (int ct = 0; ct < 4; ++ct) {
#pragma unroll
        for (int j = 0; j < 4; ++j) {
            const int t = w * 16 + lhi * 4 + j;
            const int d = N0 + ct * 16 + llo;
            Kp[(size_t)t * DD + d] = f2bf(acc[ct][j]);
        }
    }
}

// ---------------------------------------------------------------------------
// Fused main: 256 blocks x 512 thr (8 waves), 128 q-rows/block = 4 chunks x 32.
// Kp resident in LDS (128 KB, staged once); PvT resident in VGPRs (64/lane).
// Steady-state step (64 total): { stage x 8KB (1 gload/thr) | 2 QK^T MFMA |
//   C-slice of previous chunk (2 MFMA + 1 float4 store/thr) } with counted
//   vmcnt + raw barrier -> read & write streams both active every step.
// Per chunk: reduce (sSf aliases the dead A-buf) -> l2-norm*8 -> exact GELU
//   -> s' bf16 [32][128B] swizzled in sP (single buffer, barrier-separated).
// ---------------------------------------------------------------------------
__global__ __launch_bounds__(512) void pattn_kernel(
        const float* __restrict__ x, const unsigned short* __restrict__ Kp,
        const unsigned short* __restrict__ PvT, float* __restrict__ out) {
    __shared__ __align__(16) unsigned char smem[159744];
    // [0,131072)        Kp bf16 [64 tok][1024 k], 16B-chunk XOR (row&7)
    // [131072,155648)   A bufs 3 x 8192: x fp32 [32][64k], 32B-granule XOR (row&7)
    // [155648,159744)   sP: s' bf16 [32][128B], 16B-chunk XOR (row&7)
    unsigned char* KpL = smem;
    unsigned char* Ab  = smem + 131072;
    unsigned char* sP  = smem + 155648;

    const int tid = threadIdx.x;
    const int w   = tid >> 6;     // 0..7
    const int l   = tid & 63;
    const int lhi = l >> 4;       // 0..3
    const int llo = l & 15;       // 0..15
    const int wr  = w >> 2;       // 0..1  row-half of 32-row chunk
    const int wt  = w & 3;        // 0..3  token-slice
    const int R0  = blockIdx.x * 128;
    const char* xb  = (const char*)x;
    const char* kpb = (const char*)Kp;

    // ---- prologue: Kp -> LDS once (16 gloads/thread) ----
#pragma unroll
    for (int i = 0; i < 16; ++i) {
        const int seg  = w * 16 + i;          // 0..127 (1KB segments)
        const int row  = seg >> 1;
        const int half = seg & 1;
        const int cc   = half * 64 + l;       // 16B-chunk in row, 0..127
        const int csw  = cc ^ (row & 7);
        gload_lds16(kpb + (size_t)row * 2048 + csw * 16,
                    (void*)(KpL + row * 2048 + half * 1024));
    }
    // PvT -> VGPRs (held whole kernel); wave w owns d-cols w*128..+128
    const int d0 = w * 128;
    short8 pa0[8], pa1[8];
#pragma unroll
    for (int dt = 0; dt < 8; ++dt) {
        const unsigned short* ap = PvT + (size_t)(d0 + dt * 16 + llo) * 64 + lhi * 8;
        pa0[dt] = *(const short8*)ap;
        pa1[dt] = *(const short8*)(ap + 32);
    }

    // stage x K-step g (8 KB: [32 rows][64 k f32]); 1 gload/thread
#define STAGE_A(g)                                                              \
    {                                                                           \
        const int cg_  = (g) >> 4, kst_ = (g) & 15, bi_ = (g) % 3;              \
        const int row_ = w * 4 + (l >> 4);                                      \
        const int csw_ = (l & 15) ^ ((row_ & 7) << 1);                          \
        gload_lds16(xb + (size_t)(R0 + cg_ * 32 + row_) * 4096                  \
                       + kst_ * 256 + csw_ * 16,                                \
                    (void*)(Ab + bi_ * 8192 + (w * 4) * 256));                  \
    }

    // QK^T for step g: wave (wr,wt): 16 rows x 16 tokens, 2 MFMA (ks=0,1)
#define COMPUTE_A(g)                                                            \
    {                                                                           \
        const int kst_ = (g) & 15, bi_ = (g) % 3;                               \
        unsigned char* abuf_ = Ab + bi_ * 8192;                                 \
        _Pragma("unroll")                                                       \
        for (int ks = 0; ks < 2; ++ks) {                                        \
            const int btok = wt * 16 + llo;                                     \
            const int kc   = (kst_ * 8 + ks * 4 + lhi) ^ (btok & 7);            \
            const short8 bf = *(const short8*)(KpL + btok * 2048 + kc * 16);    \
            const int arow  = wr * 16 + llo;                                    \
            const int ab_   = arow * 256 + (((ks * 4 + lhi) ^ (arow & 7)) << 5);\
            const float4v f0 = *(const float4v*)(abuf_ + ab_);                  \
            const float4v f1 = *(const float4v*)(abuf_ + ab_ + 16);             \
            short8 a;                                                           \
            ((__hip_bfloat162*)&a)[0] = __float22bfloat162_rn(float2{f0.x, f0.y}); \
            ((__hip_bfloat162*)&a)[1] = __float22bfloat162_rn(float2{f0.z, f0.w}); \
            ((__hip_bfloat162*)&a)[2] = __float22bfloat162_rn(float2{f1.x, f1.y}); \
            ((__hip_bfloat162*)&a)[3] = __float22bfloat162_rn(float2{f1.z, f1.w}); \
            acc = __builtin_amdgcn_mfma_f32_16x16x32_bf16(a, bf, acc, 0, 0, 0); \
        }                                                                       \
    }

    // one 16th of previous chunk cp's PV GEMM: 2 MFMA + 1 float4 store
#define C_SLICE(cp, tt)                                                         \
    {                                                                           \
        const int dt_ = (tt) >> 1, qb_ = (tt) & 1;                              \
        const int q_  = qb_ * 16 + llo;                                         \
        const short8 s0 = *(const short8*)(sP + q_ * 128 +                      \
                              (((lhi)     ^ (q_ & 7)) << 4));                   \
        const short8 s1 = *(const short8*)(sP + q_ * 128 +                      \
                              (((4 + lhi) ^ (q_ & 7)) << 4));                   \
        f32x4 cy = (f32x4){0.f, 0.f, 0.f, 0.f};                                 \
        cy = __builtin_amdgcn_mfma_f32_16x16x32_bf16(pa0[dt_], s0, cy, 0, 0, 0);\
        cy = __builtin_amdgcn_mfma_f32_16x16x32_bf16(pa1[dt_], s1, cy, 0, 0, 0);\
        *(float4v*)(out + (size_t)(R0 + (cp) * 32 + q_) * DD                    \
                        + d0 + dt_ * 16 + lhi * 4) = cy;                        \
    }

    // chunk reduce: partials -> sSf (aliases dead A-buf c%3) -> norm -> GELU -> sP
#define REDUCE(c)                                                               \
    {                                                                           \
        __syncthreads();                                                        \
        float* sSfp = (float*)(Ab + ((c) % 3) * 8192);  /* [32][64] f32 */      \
        _Pragma("unroll")                                                       \
        for (int j = 0; j < 4; ++j)                                             \
            sSfp[(wr * 16 + lhi * 4 + j) * 64 + wt * 16 + llo] = acc[j];        \
        __syncthreads();                                                        \
        {                                                                       \
            const int r_  = tid >> 4;          /* 0..31 */                      \
            const int tq_ = tid & 15;          /* 4-token group */              \
            const f32x4 v = *(const f32x4*)(sSfp + r_ * 64 + tq_ * 4);          \
            float ssq = v.x * v.x + v.y * v.y + v.z * v.z + v.w * v.w;          \
            ssq += __shfl_xor(ssq, 1);                                          \
            ssq += __shfl_xor(ssq, 2);                                          \
            ssq += __shfl_xor(ssq, 4);                                          \
            ssq += __shfl_xor(ssq, 8);                                          \
            const float scale = 8.0f / sqrtf(ssq);                              \
            ushort4v gq;                                                        \
            _Pragma("unroll")                                                   \
            for (int k = 0; k < 4; ++k) {                                       \
                const float a_ = v[k] * scale;                                  \
                gq[k] = f2bf(0.5f * a_ * (1.0f + erff(a_ * 0.70710678118654752f))); \
            }                                                                   \
            *(ushort4v*)(sP + r_ * 128 + ((((tq_ >> 1) ^ (r_ & 7))) << 4)       \
                            + (tq_ & 1) * 8) = gq;                              \
        }                                                                       \
        __syncthreads();                                                        \
        acc = (f32x4){0.f, 0.f, 0.f, 0.f};                                      \
    }

    f32x4 acc = (f32x4){0.f, 0.f, 0.f, 0.f};

    STAGE_A(0);
    STAGE_A(1);
    __syncthreads();   // drains Kp, PvT, A(0), A(1)

    // ---- chunk 0: no C work yet; vmcnt(1) = allow next stage in flight ----
#pragma unroll
    for (int t = 0; t < 16; ++t) {
        asm volatile("s_waitcnt vmcnt(1)" ::: "memory");
        __builtin_amdgcn_s_barrier();
        __builtin_amdgcn_sched_barrier(0);
        STAGE_A(t + 2);
        COMPUTE_A(t);
    }
    REDUCE(0);

    // ---- chunks 1..3: A(c) interleaved with C(c-1) ----
#pragma unroll 1
    for (int c = 1; c < 4; ++c) {
#pragma unroll
        for (int t = 0; t < 16; ++t) {
            // FIFO: [A(g), s(t-2), A(g+1), s(t-1)] -> vmcnt(3) retires A(g);
            // t=15: stage stream may have ended -> vmcnt(2).
            if (t == 15) { asm volatile("s_waitcnt vmcnt(2)" ::: "memory"); }
            else         { asm volatile("s_waitcnt vmcnt(3)" ::: "memory"); }
            __builtin_amdgcn_s_barrier();
            __builtin_amdgcn_sched_barrier(0);
            const int g = c * 16 + t;
            if (g + 2 < 64) STAGE_A(g + 2);
            COMPUTE_A(g);
            C_SLICE(c - 1, t);
        }
        REDUCE(c);
    }

    // ---- tail: drain C(3) ----
#pragma unroll
    for (int t = 0; t < 16; ++t) {
        C_SLICE(3, t);
    }

#undef STAGE_A
#undef COMPUTE_A
#undef C_SLICE
#undef REDUCE
}

// ---------------------------------------------------------------------------
extern "C" void kernel_launch(void* const* d_in, const int* in_sizes, int n_in,
                              void* d_out, int out_size, void* d_ws, size_t ws_size,
                              hipStream_t stream) {
    (void)in_sizes; (void)n_in; (void)out_size; (void)ws_size;
    const float* x  = (const float*)d_in[0];
    const float* Wq = (const float*)d_in[1];
    const float* Pk = (const float*)d_in[2];
    const float* Pv = (const float*)d_in[3];
    float* out = (float*)d_out;

    // ws layout (2.25 MB total):
    //   WqT bf16 [1024][1024] @ 0            (2 MB)
    //   Kp  bf16 [64][1024]   @ 2 MB         (128 KB)
    //   PvT bf16 [1024][64]   @ 2 MB + 128K  (128 KB)
    unsigned short* WqT = (unsigned short*)d_ws;
    unsigned short* Kp  = (unsigned short*)((char*)d_ws + 2097152);
    unsigned short* PvT = (unsigned short*)((char*)d_ws + 2097152 + 131072);

    prep_transpose_kernel<<<272, 256, 0, stream>>>(Wq, Pv, WqT, PvT);
    kp_mfma_kernel<<<16, 256, 0, stream>>>(Pk, WqT, Kp);
    pattn_kernel<<<256, 512, 0, stream>>>(x, Kp, PvT, out);
}